// Round 1
// baseline (89.100 us; speedup 1.0000x reference)
//
#include <hip/hip_runtime.h>
#include <math.h>

#define SRf 48000.0f
#define CSOUND 343.0f
#define RIR_LEN 24000
#define TAPS 81
#define HALFT 40
#define NB 8
#define NM 21                 // per-axis entries with order <= 10
#define NTRIP (NM * NM * NM)  // 9261

// 0.9^q for q = 0..10 (computed in double, rounded to f32)
__device__ __constant__ float c_beta[11] = {
    1.0f, 0.9f, 0.81f, 0.729f, 0.6561f, 0.59049f, 0.531441f,
    0.4782969f, 0.43046721f, 0.387420489f, 0.3486784401f};

// Per-axis image table restricted to order <= 10:
//   m in [0,10]:  p=0, n=m-5  -> sign=+1, off=2n, order=2|n|
//   m in [11,20]: p=1, n=m-15 -> sign=-1, off=2n, order=|n-1|+|n|
__device__ __forceinline__ void axis_entry(int m, float& sgn, float& off, int& ord) {
    if (m < 11) {
        int n = m - 5;
        sgn = 1.0f;
        off = 2.0f * (float)n;
        ord = 2 * abs(n);
    } else {
        int n = m - 15;
        sgn = -1.0f;
        off = 2.0f * (float)n;
        ord = abs(n - 1) + abs(n);
    }
}

__global__ void rir_kernel(const float* __restrict__ x, float* __restrict__ out) {
    const float PIF = 3.14159265358979323846f;
    int t = blockIdx.x * blockDim.x + threadIdx.x;

    // fold the 8 origin outputs into the first threads
    if (t < NB) {
        const float* xb = x + t * 9;
        float r0 = xb[0] * 10.0f, r1 = xb[1] * 10.0f, r2 = xb[2] * 10.0f;
        float d0 = xb[3] * r0 - xb[6] * r0;
        float d1 = xb[4] * r1 - xb[7] * r1;
        float d2 = xb[5] * r2 - xb[8] * r2;
        float dist = sqrtf(d0 * d0 + d1 * d1 + d2 * d2);
        out[NB * RIR_LEN + t] = 40.0f + SRf * dist / CSOUND;
    }

    if (t >= NB * NTRIP) return;
    int b = t / NTRIP;
    int r = t - b * NTRIP;
    int mi = r / (NM * NM);
    int mj = (r / NM) % NM;
    int mk = r % NM;

    float si, oi_;
    int qi;
    axis_entry(mi, si, oi_, qi);
    float sj, oj_;
    int qj;
    axis_entry(mj, sj, oj_, qj);
    float sk, ok_;
    int qk;
    axis_entry(mk, sk, ok_, qk);

    int q = qi + qj + qk;
    if (q > 10) return;

    const float* xb = x + b * 9;
    float r0 = xb[0] * 10.0f, r1 = xb[1] * 10.0f, r2 = xb[2] * 10.0f;
    float m0 = xb[3] * r0, m1 = xb[4] * r1, m2 = xb[5] * r2;
    float s0 = xb[6] * r0, s1 = xb[7] * r1, s2 = xb[8] * r2;

    float dx = si * s0 + oi_ * r0 - m0;
    float dy = sj * s1 + oj_ * r1 - m1;
    float dz = sk * s2 + ok_ * r2 - m2;
    float dist = sqrtf(dx * dx + dy * dy + dz * dz);

    float amp = c_beta[q] / (4.0f * PIF * dist);
    float tau = SRf * dist / CSOUND;
    float i0f = floorf(tau);
    float frac = tau - i0f;
    int i0 = (int)i0f;

    // sin(pi*(k - frac)) = (k odd ? +1 : -1) * sin(pi*frac)   (k = ki-40, 40 even)
    float spf = sinf(PIF * frac);
    float* rb = out + b * RIR_LEN;

    for (int ki = 0; ki < TAPS; ++ki) {
        int idx = i0 + HALFT + ki;
        if (idx < 0 || idx >= RIR_LEN) continue;
        float tt = (float)(ki - HALFT) - frac;
        if (fabsf(tt) > (float)HALFT) continue;  // window support
        float win = 0.5f * (1.0f + cosf(PIF * tt * (1.0f / 41.0f)));
        float snc = (tt == 0.0f) ? 1.0f : (((ki & 1) ? spf : -spf) / (PIF * tt));
        atomicAdd(&rb[idx], amp * snc * win);
    }
}

extern "C" void kernel_launch(void* const* d_in, const int* in_sizes, int n_in,
                              void* d_out, int out_size, void* d_ws, size_t ws_size,
                              hipStream_t stream) {
    const float* x = (const float*)d_in[0];
    float* out = (float*)d_out;

    hipMemsetAsync(out, 0, (size_t)out_size * sizeof(float), stream);

    int total = NB * NTRIP;
    int block = 256;
    int grid = (total + block - 1) / block;
    rir_kernel<<<grid, block, 0, stream>>>(x, out);
}